// Round 7
// baseline (1387.260 us; speedup 1.0000x reference)
//
#include <hip/hip_runtime.h>
#include <hip/hip_bf16.h>
#include <stdint.h>

#define M_DIM 8192
#define N_DIM 16384
#define K_DIM 4096

typedef short short8 __attribute__((ext_vector_type(8)));
typedef float floatx4 __attribute__((ext_vector_type(4)));
typedef int i32x4 __attribute__((ext_vector_type(4)));

__device__ __forceinline__ unsigned short f2bf(float f) {
    union { float f; unsigned u; } a;
    a.f = f;
    unsigned r = a.u + 0x7FFFu + ((a.u >> 16) & 1u);
    return (unsigned short)(r >> 16);
}

#define GLDS16(g, l)                                                     \
    __builtin_amdgcn_global_load_lds(                                    \
        (const __attribute__((address_space(1))) void*)(g),              \
        (__attribute__((address_space(3))) void*)(l), 16, 0, 0)

#define SBAR() asm volatile("s_barrier" ::: "memory")
#define WAIT_VM0() asm volatile("s_waitcnt vmcnt(0)" ::: "memory")
#define WAIT_VM2() asm volatile("s_waitcnt vmcnt(2)" ::: "memory")
#define WAIT_VM8() asm volatile("s_waitcnt vmcnt(8)" ::: "memory")

// ---------------- x: per-row int8 quant (scale sx[row] = absmax/127) ----------
__global__ __launch_bounds__(256)
void quant_x_kernel(const float4* __restrict__ x, int* __restrict__ xq,
                    float* __restrict__ sx) {
    const int row = blockIdx.x;
    const int t = threadIdx.x;
    const float4* px = x + (size_t)row * (K_DIM / 4);
    float4 v[4];
    float am = 0.f;
#pragma unroll
    for (int j = 0; j < 4; ++j) {
        v[j] = px[t + j * 256];
        am = fmaxf(am, fmaxf(fmaxf(fabsf(v[j].x), fabsf(v[j].y)),
                             fmaxf(fabsf(v[j].z), fabsf(v[j].w))));
    }
#pragma unroll
    for (int m = 32; m; m >>= 1) am = fmaxf(am, __shfl_xor(am, m));
    __shared__ float red[4];
    if ((t & 63) == 0) red[t >> 6] = am;
    __syncthreads();
    am = fmaxf(fmaxf(red[0], red[1]), fmaxf(red[2], red[3]));
    const float inv = am > 0.f ? 127.f / am : 0.f;
    if (t == 0) sx[row] = am * (1.f / 127.f);
    int* xo = xq + (size_t)row * (K_DIM / 4);
#pragma unroll
    for (int j = 0; j < 4; ++j) {
        int q0 = (int)rintf(v[j].x * inv);
        int q1 = (int)rintf(v[j].y * inv);
        int q2 = (int)rintf(v[j].z * inv);
        int q3 = (int)rintf(v[j].w * inv);
        xo[t + j * 256] = (q0 & 255) | ((q1 & 255) << 8) |
                          ((q2 & 255) << 16) | ((q3 & 255) << 24);
    }
}

// ---------------- w: int32 -> int8 (q - zp), exact ----------------
__global__ void cvt_w8_kernel(const int4* __restrict__ w, int4* __restrict__ out,
                              const int* __restrict__ zp_p, int n16) {
    const int zp = *zp_p;
    int idx = blockIdx.x * blockDim.x + threadIdx.x;
    int stride = gridDim.x * blockDim.x;
    for (int i = idx; i < n16; i += stride) {
        int4 r;
        int* rp = (int*)&r;
#pragma unroll
        for (int j = 0; j < 4; ++j) {
            int4 q = w[i * 4 + j];
            rp[j] = ((q.x - zp) & 255) | (((q.y - zp) & 255) << 8) |
                    (((q.z - zp) & 255) << 16) | (((q.w - zp) & 255) << 24);
        }
        out[i] = r;
    }
}

// ======== 256x256 int8 GEMM: content-rotation schedule (reg-neutral) =========
// LDS layout / swizzle / staging addresses identical to R4 (verified, 0
// conflicts). Quadrant order Q00->Q01->Q11->Q10; each fragment set reloads
// next-tile content in the SAME registers immediately AFTER its last MFMA use
// (reg-WAR pins order; MFMA latches operands at issue). All ds_reads execute
// under later MFMA windows. 4 barriers/K-tile. Counted vmcnt pair: VM8@ph1
// (oldest-8-retired => cur buffer complete), VM2@ph2 (next buffer A0/B0/B1
// landed); A1-next is forced by the NEXT tile's VM8. lgkm: compiler-auto.
// Fragment regs = 64 (same as R4, which did not spill).

#define LOAD_AR(BUF, MH, AF)                                               \
    do {                                                                   \
        const char* p_ = smem + (BUF)*65536 + (MH)*16384 + wm*8192;        \
        _Pragma("unroll") for (int mf = 0; mf < 4; ++mf) {                 \
            AF[mf][0] = *(const i32x4*)(p_ + mf*2048 + laneK0);            \
            AF[mf][1] = *(const i32x4*)(p_ + mf*2048 + laneK1);            \
        }                                                                  \
    } while (0)

#define LOAD_BR(BUF, NH, BF)                                               \
    do {                                                                   \
        const char* p_ = smem + (BUF)*65536 + 32768 + (NH)*16384 + wn*4096;\
        _Pragma("unroll") for (int nf = 0; nf < 2; ++nf) {                 \
            BF[nf][0] = *(const i32x4*)(p_ + nf*2048 + laneK0);            \
            BF[nf][1] = *(const i32x4*)(p_ + nf*2048 + laneK1);            \
        }                                                                  \
    } while (0)

#define STAGE_A0(BUF)                                                      \
    do {                                                                   \
        GLDS16(pA00, smem + (BUF)*65536 + st16); pA00 += 128;              \
        GLDS16(pA01, smem + (BUF)*65536 + 8192 + st16); pA01 += 128;       \
    } while (0)
#define STAGE_A1(BUF)                                                      \
    do {                                                                   \
        GLDS16(pA10, smem + (BUF)*65536 + 16384 + st16); pA10 += 128;      \
        GLDS16(pA11, smem + (BUF)*65536 + 16384 + 8192 + st16); pA11 += 128;\
    } while (0)
#define STAGE_B0(BUF)                                                      \
    do {                                                                   \
        GLDS16(pB00, smem + (BUF)*65536 + 32768 + st16); pB00 += 128;      \
        GLDS16(pB01, smem + (BUF)*65536 + 32768 + 8192 + st16); pB01 += 128;\
    } while (0)
#define STAGE_B1(BUF)                                                      \
    do {                                                                   \
        GLDS16(pB10, smem + (BUF)*65536 + 49152 + st16); pB10 += 128;      \
        GLDS16(pB11, smem + (BUF)*65536 + 49152 + 8192 + st16); pB11 += 128;\
    } while (0)

#define MFMA_Q(AF, BF, MH, NH)                                             \
    do {                                                                   \
        __builtin_amdgcn_s_setprio(1);                                     \
        _Pragma("unroll") for (int kk = 0; kk < 2; ++kk)                   \
        _Pragma("unroll") for (int mf = 0; mf < 4; ++mf)                   \
        _Pragma("unroll") for (int nf = 0; nf < 2; ++nf)                   \
            acc[(MH)*4+mf][(NH)*2+nf] =                                    \
                __builtin_amdgcn_mfma_i32_16x16x64_i8(                     \
                    AF[mf][kk], BF[nf][kk], acc[(MH)*4+mf][(NH)*2+nf],     \
                    0, 0, 0);                                              \
        __builtin_amdgcn_s_setprio(0);                                     \
    } while (0)

// SMODE: 2 steady (stage kt+2 + prefetch kt+1), 1 = kt==NT-2 (prefetch only),
// 0 = kt==NT-1 (nothing). Reads for CURRENT tile: only aF1 (ph1, post-MFMA).
#define BODY(B, NB, SMODE)                                                 \
    do {                                                                   \
        /* ph1: Q00(aF0,bF0); reload aF1 <- A1(kt) from cur */             \
        if ((SMODE) == 2) { WAIT_VM8(); } else { WAIT_VM0(); }             \
        SBAR();                                                            \
        MFMA_Q(aF0, bF0, 0, 0);                                            \
        LOAD_AR(B, 1, aF1);                                                \
        /* ph2: Q01(aF0,bF1); aF0 dead -> reload A0(kt+1) from nxt */      \
        SBAR();                                                            \
        WAIT_VM2();                                                        \
        MFMA_Q(aF0, bF1, 0, 1);                                            \
        if ((SMODE) >= 1) LOAD_AR(NB, 0, aF0);                             \
        if ((SMODE) == 2) { STAGE_A0(B); STAGE_B0(B); }                    \
        /* ph3: Q11(aF1,bF1); bF1 dead -> reload B1(kt+1) */               \
        SBAR();                                                            \
        MFMA_Q(aF1, bF1, 1, 1);                                            \
        if ((SMODE) >= 1) LOAD_BR(NB, 1, bF1);                             \
        if ((SMODE) == 2) STAGE_B1(B);                                     \
        /* ph4: Q10(aF1,bF0); bF0 dead -> reload B0(kt+1) */               \
        SBAR();                                                            \
        MFMA_Q(aF1, bF0, 1, 0);                                            \
        if ((SMODE) >= 1) LOAD_BR(NB, 0, bF0);                             \
        if ((SMODE) == 2) STAGE_A1(B);                                     \
    } while (0)

__global__ __launch_bounds__(512, 2)
void gemm8i_kernel(const int8_t* __restrict__ Aq, const int8_t* __restrict__ Bq,
                   const float* __restrict__ bias,
                   const float* __restrict__ scale_p,
                   const float* __restrict__ sx,
                   float* __restrict__ out) {
    __shared__ __align__(16) char smem[131072];

    const int t = threadIdx.x;
    const int lane = t & 63;
    const int wid = t >> 6;
    const int wm = wid >> 2;  // 0..1
    const int wn = wid & 3;   // 0..3

    // XCD-aware bijective swizzle (nwg=2048 divisible by 8)
    int bid = blockIdx.x;
    int sz = (bid & 7) * 256 + (bid >> 3);
    const int bx = sz & 63;
    const int by = sz >> 6;
    const int brow = by << 8;
    const int bcol = bx << 8;

    // swizzled ds_read lane offsets (128B rows, 16B slots)
    const int laneK0 = (lane & 15) * 128 + (((lane >> 4) * 16) ^ ((lane & 7) << 4));
    const int laneK1 = (lane & 15) * 128 + ((((lane >> 4) * 16) + 64) ^ ((lane & 7) << 4));

    // staging source offsets (inverse-swizzled); 1 byte per element
    size_t aoffs[2], boffs[2];
#pragma unroll
    for (int g = 0; g < 2; ++g) {
        unsigned u = g * 8192 + t * 16;
        unsigned up = u ^ (((u >> 7) & 7) << 4);
        aoffs[g] = (size_t)(brow + ((up >> 13) & 1) * 128 + ((up >> 7) & 63)) * K_DIM
                   + (up & 127);
        boffs[g] = (size_t)(bcol + ((up >> 12) & 3) * 64 + ((up >> 7) & 31)) * K_DIM
                   + (up & 127);
    }
    const int8_t* pA00 = Aq + aoffs[0];
    const int8_t* pA01 = Aq + aoffs[1];
    const int8_t* pA10 = Aq + aoffs[0] + 262144;   // +64 rows
    const int8_t* pA11 = Aq + aoffs[1] + 262144;
    const int8_t* pB00 = Bq + boffs[0];
    const int8_t* pB01 = Bq + boffs[1];
    const int8_t* pB10 = Bq + boffs[0] + 131072;   // +32 cols
    const int8_t* pB11 = Bq + boffs[1] + 131072;
    const int st16 = t * 16;

    i32x4 acc[8][4] = {};
    i32x4 aF0[4][2], aF1[4][2], bF0[2][2], bF1[2][2];

    const int NT = K_DIM / 128;  // 32

    // ---- prologue: stage tile0 (buf0) + tile1 (buf1); wait tile0; preload
    STAGE_A0(0); STAGE_B0(0); STAGE_B1(0); STAGE_A1(0);
    STAGE_A0(1); STAGE_B0(1); STAGE_B1(1); STAGE_A1(1);
    WAIT_VM8();               // tile0 complete (8 newest outstanding = tile1)
    SBAR();
    LOAD_AR(0, 0, aF0);
    LOAD_BR(0, 0, bF0);
    LOAD_BR(0, 1, bF1);

    // ---- main loop: 15 iters x 2 K-tiles (kt = 0..29), branchless
    for (int it = 0; it < (NT - 2) / 2; ++it) {
        BODY(0, 1, 2);
        BODY(1, 0, 2);
    }
    // ---- tail: kt = NT-2 (buf0), kt = NT-1 (buf1)
    BODY(0, 1, 1);
    BODY(1, 0, 0);

    // ---- epilogue: out = acc * (scale*sx[row]) + bias[col]
    const float scale = *scale_p;
    const int crow0 = brow + wm * 128 + ((lane >> 4) << 2);
    const int ccol0 = bcol + wn * 64 + (lane & 15);
    float bv[4];
#pragma unroll
    for (int nf = 0; nf < 4; ++nf) bv[nf] = bias[ccol0 + nf * 16];
#pragma unroll
    for (int mf = 0; mf < 8; ++mf) {
#pragma unroll
        for (int j = 0; j < 4; ++j) {
            const int r = crow0 + mf * 16 + j;
            const float s2 = scale * sx[r];
            float* orow = out + (size_t)r * N_DIM;
#pragma unroll
            for (int nf = 0; nf < 4; ++nf)
                orow[ccol0 + nf * 16] = (float)acc[mf][nf][j] * s2 + bv[nf];
        }
    }
}

// ---------------- fallback (ws too small): fused dequant 128^2 bf16 GEMM ------
__global__ __launch_bounds__(256)
void gemm_fb_kernel(const float* __restrict__ Xf, const int* __restrict__ Wq,
                    const float* __restrict__ bias,
                    const float* __restrict__ scale_p,
                    const int* __restrict__ zp_p,
                    float* __restrict__ out) {
    const int NB = N_DIM / 128;
    int nwg = gridDim.x;
    int cpx = nwg >> 3;
    int bid = blockIdx.x;
    int swz = (bid & 7) * cpx + (bid >> 3);
    int bx = swz % NB;
    int by = swz / NB;
    const int brow = by * 128;
    const int bcol = bx * 128;

    __shared__ __align__(16) ushort sA[128 * 32];
    __shared__ __align__(16) ushort sB[128 * 32];

    const int t = threadIdx.x;
    const int lane = t & 63;
    const int wid = t >> 6;
    const int wr = wid >> 1;
    const int wc = wid & 1;

    floatx4 acc[4][4] = {};

    const int xr = t >> 1;
    const int xc = (t & 1) << 4;
    const int zp = *zp_p;

    const int arow = wr * 64 + (lane & 15);
    const int acol = (lane >> 4) << 3;
    const int brow_f = wc * 64 + (lane & 15);

    for (int k0 = 0; k0 < K_DIM; k0 += 32) {
        __syncthreads();
        const float* gx = Xf + (size_t)(brow + xr) * K_DIM + k0 + xc;
        ushort* dA = &sA[xr * 32 + xc];
#pragma unroll
        for (int i = 0; i < 4; ++i) {
            float4 v = ((const float4*)gx)[i];
            ushort4 u;
            u.x = f2bf(v.x); u.y = f2bf(v.y); u.z = f2bf(v.z); u.w = f2bf(v.w);
            *(ushort4*)(dA + i * 4) = u;
        }
        const int* gw = Wq + (size_t)(bcol + xr) * K_DIM + k0 + xc;
        ushort* dB = &sB[xr * 32 + xc];
#pragma unroll
        for (int i = 0; i < 4; ++i) {
            int4 q = ((const int4*)gw)[i];
            ushort4 u;
            u.x = f2bf((float)(q.x - zp));
            u.y = f2bf((float)(q.y - zp));
            u.z = f2bf((float)(q.z - zp));
            u.w = f2bf((float)(q.w - zp));
            *(ushort4*)(dB + i * 4) = u;
        }
        __syncthreads();

        short8 af[4], bfr[4];
#pragma unroll
        for (int m = 0; m < 4; ++m)
            af[m] = *(const short8*)&sA[(arow + m * 16) * 32 + acol];
#pragma unroll
        for (int n = 0; n < 4; ++n)
            bfr[n] = *(const short8*)&sB[(brow_f + n * 16) * 32 + acol];

#pragma unroll
        for (int m = 0; m < 4; ++m)
#pragma unroll
            for (int n = 0; n < 4; ++n)
                acc[m][n] = __builtin_amdgcn_mfma_f32_16x16x32_bf16(
                    af[m], bfr[n], acc[m][n], 0, 0, 0);
    }

    const float scale = *scale_p;
    const int colbase = bcol + wc * 64 + (lane & 15);
    const int rowbase = brow + wr * 64 + ((lane >> 4) << 2);
    float bv[4];
#pragma unroll
    for (int n = 0; n < 4; ++n) bv[n] = bias[colbase + n * 16];
#pragma unroll
    for (int m = 0; m < 4; ++m) {
        const int r0 = rowbase + m * 16;
#pragma unroll
        for (int j = 0; j < 4; ++j) {
            float* orow = out + (size_t)(r0 + j) * N_DIM;
#pragma unroll
            for (int n = 0; n < 4; ++n)
                orow[colbase + n * 16] = acc[m][n][j] * scale + bv[n];
        }
    }
}

extern "C" void kernel_launch(void* const* d_in, const int* in_sizes, int n_in,
                              void* d_out, int out_size, void* d_ws, size_t ws_size,
                              hipStream_t stream) {
    const float* x = (const float*)d_in[0];
    const int* wq = (const int*)d_in[1];
    const float* bias = (const float*)d_in[2];
    const float* scale = (const float*)d_in[3];
    const int* zp = (const int*)d_in[4];
    float* out = (float*)d_out;

    const size_t xq_bytes = (size_t)M_DIM * K_DIM;       // 32 MiB
    const size_t wb_bytes = (size_t)N_DIM * K_DIM;       // 64 MiB
    const size_t sx_bytes = (size_t)M_DIM * 4;           // 32 KiB

    if (ws_size >= xq_bytes + wb_bytes + sx_bytes) {
        int8_t* xq = (int8_t*)d_ws;
        int8_t* wb = (int8_t*)d_ws + xq_bytes;
        float* sx = (float*)((char*)d_ws + xq_bytes + wb_bytes);
        quant_x_kernel<<<M_DIM, 256, 0, stream>>>((const float4*)x, (int*)xq, sx);
        cvt_w8_kernel<<<2048, 256, 0, stream>>>((const int4*)wq, (int4*)wb, zp,
                                                (N_DIM * K_DIM) / 16);
        const int nblocks = (M_DIM / 256) * (N_DIM / 256);  // 2048
        gemm8i_kernel<<<nblocks, 512, 0, stream>>>(xq, wb, bias, scale, sx, out);
    } else {
        const int nblocks = (M_DIM / 128) * (N_DIM / 128);
        gemm_fb_kernel<<<nblocks, 256, 0, stream>>>(x, wq, bias, scale, zp, out);
    }
}

// Round 8
// 1253.976 us; speedup vs baseline: 1.1063x; 1.1063x over previous
//
#include <hip/hip_runtime.h>
#include <hip/hip_bf16.h>
#include <stdint.h>

#define M_DIM 8192
#define N_DIM 16384
#define K_DIM 4096

typedef short short8 __attribute__((ext_vector_type(8)));
typedef float floatx4 __attribute__((ext_vector_type(4)));
typedef int i32x4 __attribute__((ext_vector_type(4)));

__device__ __forceinline__ unsigned short f2bf(float f) {
    union { float f; unsigned u; } a;
    a.f = f;
    unsigned r = a.u + 0x7FFFu + ((a.u >> 16) & 1u);
    return (unsigned short)(r >> 16);
}

#define GLDS16(g, l)                                                     \
    __builtin_amdgcn_global_load_lds(                                    \
        (const __attribute__((address_space(1))) void*)(g),              \
        (__attribute__((address_space(3))) void*)(l), 16, 0, 0)

#define SBAR() asm volatile("s_barrier" ::: "memory")
#define WAIT_VM0() asm volatile("s_waitcnt vmcnt(0)" ::: "memory")
#define WAIT_VM8() asm volatile("s_waitcnt vmcnt(8)" ::: "memory")

// ---------------- x: per-row int8 quant (scale sx[row] = absmax/127) ----------
__global__ __launch_bounds__(256)
void quant_x_kernel(const float4* __restrict__ x, int* __restrict__ xq,
                    float* __restrict__ sx) {
    const int row = blockIdx.x;
    const int t = threadIdx.x;
    const float4* px = x + (size_t)row * (K_DIM / 4);
    float4 v[4];
    float am = 0.f;
#pragma unroll
    for (int j = 0; j < 4; ++j) {
        v[j] = px[t + j * 256];
        am = fmaxf(am, fmaxf(fmaxf(fabsf(v[j].x), fabsf(v[j].y)),
                             fmaxf(fabsf(v[j].z), fabsf(v[j].w))));
    }
#pragma unroll
    for (int m = 32; m; m >>= 1) am = fmaxf(am, __shfl_xor(am, m));
    __shared__ float red[4];
    if ((t & 63) == 0) red[t >> 6] = am;
    __syncthreads();
    am = fmaxf(fmaxf(red[0], red[1]), fmaxf(red[2], red[3]));
    const float inv = am > 0.f ? 127.f / am : 0.f;
    if (t == 0) sx[row] = am * (1.f / 127.f);
    int* xo = xq + (size_t)row * (K_DIM / 4);
#pragma unroll
    for (int j = 0; j < 4; ++j) {
        int q0 = (int)rintf(v[j].x * inv);
        int q1 = (int)rintf(v[j].y * inv);
        int q2 = (int)rintf(v[j].z * inv);
        int q3 = (int)rintf(v[j].w * inv);
        xo[t + j * 256] = (q0 & 255) | ((q1 & 255) << 8) |
                          ((q2 & 255) << 16) | ((q3 & 255) << 24);
    }
}

// ---------------- w: int32 -> int8 (q - zp), exact ----------------
__global__ void cvt_w8_kernel(const int4* __restrict__ w, int4* __restrict__ out,
                              const int* __restrict__ zp_p, int n16) {
    const int zp = *zp_p;
    int idx = blockIdx.x * blockDim.x + threadIdx.x;
    int stride = gridDim.x * blockDim.x;
    for (int i = idx; i < n16; i += stride) {
        int4 r;
        int* rp = (int*)&r;
#pragma unroll
        for (int j = 0; j < 4; ++j) {
            int4 q = w[i * 4 + j];
            rp[j] = ((q.x - zp) & 255) | (((q.y - zp) & 255) << 8) |
                    (((q.z - zp) & 255) << 16) | (((q.w - zp) & 255) << 24);
        }
        out[i] = r;
    }
}

// ====== 256x256 int8 GEMM: single-window body, cross-wave slip schedule ======
// LDS layout / swizzle / staging addresses identical to R4 (verified, 0
// conflicts). Body(kt), buf b=kt&1:
//   WAIT_VM8 (retire own staging from body kt-2 -> tile kt resident; newest 8
//   in flight = body kt-1's)  ->  SBAR  (all waves' tile-kt staging visible)
//   -> ONE window: 24 ds_reads + 64 MFMA, no internal barriers. Compiler emits
//   fine-grained lgkmcnt per MFMA dependency; the 8 waves desynchronize inside
//   the window so LDS-port time and MFMA-pipe time overlap ACROSS waves (no
//   extra registers -> no spill, unlike R5-R7).
//   -> SBAR (all waves' reads of buf b done: every read feeds an MFMA issued
//   before this point)  ->  stage buf b for tile kt+2 (8 gloads; writes land
//   after the barrier => WAR-safe; retired by VM8 at body kt+2).
// 2 barriers per K-tile (R4 had 8). Fragment regs = 96 live like R4 (no spill
// at 124 VGPR + 128 AGPR acc).

#define LOAD_AR(BUF, MH, AF)                                               \
    do {                                                                   \
        const char* p_ = smem + (BUF)*65536 + (MH)*16384 + wm*8192;        \
        _Pragma("unroll") for (int mf = 0; mf < 4; ++mf) {                 \
            AF[mf][0] = *(const i32x4*)(p_ + mf*2048 + laneK0);            \
            AF[mf][1] = *(const i32x4*)(p_ + mf*2048 + laneK1);            \
        }                                                                  \
    } while (0)

#define LOAD_BR(BUF, NH, BF)                                               \
    do {                                                                   \
        const char* p_ = smem + (BUF)*65536 + 32768 + (NH)*16384 + wn*4096;\
        _Pragma("unroll") for (int nf = 0; nf < 2; ++nf) {                 \
            BF[nf][0] = *(const i32x4*)(p_ + nf*2048 + laneK0);            \
            BF[nf][1] = *(const i32x4*)(p_ + nf*2048 + laneK1);            \
        }                                                                  \
    } while (0)

#define STAGE_A0(BUF)                                                      \
    do {                                                                   \
        GLDS16(pA00, smem + (BUF)*65536 + st16); pA00 += 128;              \
        GLDS16(pA01, smem + (BUF)*65536 + 8192 + st16); pA01 += 128;       \
    } while (0)
#define STAGE_A1(BUF)                                                      \
    do {                                                                   \
        GLDS16(pA10, smem + (BUF)*65536 + 16384 + st16); pA10 += 128;      \
        GLDS16(pA11, smem + (BUF)*65536 + 16384 + 8192 + st16); pA11 += 128;\
    } while (0)
#define STAGE_B0(BUF)                                                      \
    do {                                                                   \
        GLDS16(pB00, smem + (BUF)*65536 + 32768 + st16); pB00 += 128;      \
        GLDS16(pB01, smem + (BUF)*65536 + 32768 + 8192 + st16); pB01 += 128;\
    } while (0)
#define STAGE_B1(BUF)                                                      \
    do {                                                                   \
        GLDS16(pB10, smem + (BUF)*65536 + 49152 + st16); pB10 += 128;      \
        GLDS16(pB11, smem + (BUF)*65536 + 49152 + 8192 + st16); pB11 += 128;\
    } while (0)

#define MFMA_Q(AF, BF, MH, NH)                                             \
    do {                                                                   \
        __builtin_amdgcn_s_setprio(1);                                     \
        _Pragma("unroll") for (int kk = 0; kk < 2; ++kk)                   \
        _Pragma("unroll") for (int mf = 0; mf < 4; ++mf)                   \
        _Pragma("unroll") for (int nf = 0; nf < 2; ++nf)                   \
            acc[(MH)*4+mf][(NH)*2+nf] =                                    \
                __builtin_amdgcn_mfma_i32_16x16x64_i8(                     \
                    AF[mf][kk], BF[nf][kk], acc[(MH)*4+mf][(NH)*2+nf],     \
                    0, 0, 0);                                              \
        __builtin_amdgcn_s_setprio(0);                                     \
    } while (0)

// SMODE: 2 = steady (VM8 + stage kt+2); 1 = kt==NT-2 (VM8, no stage);
//        0 = kt==NT-1 (VM0, no stage).
#define BODY(B, SMODE)                                                     \
    do {                                                                   \
        if ((SMODE) == 0) { WAIT_VM0(); } else { WAIT_VM8(); }             \
        SBAR();                                                            \
        LOAD_AR(B, 0, aF0);                                                \
        LOAD_BR(B, 0, bF0);                                                \
        LOAD_BR(B, 1, bF1);                                                \
        LOAD_AR(B, 1, aF1);                                                \
        MFMA_Q(aF0, bF0, 0, 0);                                            \
        MFMA_Q(aF0, bF1, 0, 1);                                            \
        MFMA_Q(aF1, bF1, 1, 1);                                            \
        MFMA_Q(aF1, bF0, 1, 0);                                            \
        SBAR();                                                            \
        if ((SMODE) == 2) {                                                \
            STAGE_A0(B); STAGE_B0(B); STAGE_B1(B); STAGE_A1(B);            \
        }                                                                  \
    } while (0)

__global__ __launch_bounds__(512, 2)
void gemm8i_kernel(const int8_t* __restrict__ Aq, const int8_t* __restrict__ Bq,
                   const float* __restrict__ bias,
                   const float* __restrict__ scale_p,
                   const float* __restrict__ sx,
                   float* __restrict__ out) {
    __shared__ __align__(16) char smem[131072];

    const int t = threadIdx.x;
    const int lane = t & 63;
    const int wid = t >> 6;
    const int wm = wid >> 2;  // 0..1
    const int wn = wid & 3;   // 0..3

    // XCD-aware bijective swizzle (nwg=2048 divisible by 8)
    int bid = blockIdx.x;
    int sz = (bid & 7) * 256 + (bid >> 3);
    const int bx = sz & 63;
    const int by = sz >> 6;
    const int brow = by << 8;
    const int bcol = bx << 8;

    // swizzled ds_read lane offsets (128B rows, 16B slots)
    const int laneK0 = (lane & 15) * 128 + (((lane >> 4) * 16) ^ ((lane & 7) << 4));
    const int laneK1 = (lane & 15) * 128 + ((((lane >> 4) * 16) + 64) ^ ((lane & 7) << 4));

    // staging source offsets (inverse-swizzled); 1 byte per element
    size_t aoffs[2], boffs[2];
#pragma unroll
    for (int g = 0; g < 2; ++g) {
        unsigned u = g * 8192 + t * 16;
        unsigned up = u ^ (((u >> 7) & 7) << 4);
        aoffs[g] = (size_t)(brow + ((up >> 13) & 1) * 128 + ((up >> 7) & 63)) * K_DIM
                   + (up & 127);
        boffs[g] = (size_t)(bcol + ((up >> 12) & 3) * 64 + ((up >> 7) & 31)) * K_DIM
                   + (up & 127);
    }
    const int8_t* pA00 = Aq + aoffs[0];
    const int8_t* pA01 = Aq + aoffs[1];
    const int8_t* pA10 = Aq + aoffs[0] + 262144;   // +64 rows
    const int8_t* pA11 = Aq + aoffs[1] + 262144;
    const int8_t* pB00 = Bq + boffs[0];
    const int8_t* pB01 = Bq + boffs[1];
    const int8_t* pB10 = Bq + boffs[0] + 131072;   // +32 cols
    const int8_t* pB11 = Bq + boffs[1] + 131072;
    const int st16 = t * 16;

    i32x4 acc[8][4] = {};
    i32x4 aF0[4][2], aF1[4][2], bF0[2][2], bF1[2][2];

    const int NT = K_DIM / 128;  // 32

    // ---- prologue: stage tile0 -> buf0, tile1 -> buf1 (16 loads, no wait)
    STAGE_A0(0); STAGE_B0(0); STAGE_B1(0); STAGE_A1(0);
    STAGE_A0(1); STAGE_B0(1); STAGE_B1(1); STAGE_A1(1);

    // ---- main loop: bodies 0..29 steady, branchless
    for (int it = 0; it < (NT - 2) / 2; ++it) {
        BODY(0, 2);
        BODY(1, 2);
    }
    // ---- tail: kt = NT-2 (buf0, no stage), kt = NT-1 (buf1, full drain)
    BODY(0, 1);
    BODY(1, 0);

    // ---- epilogue: out = acc * (scale*sx[row]) + bias[col]
    const float scale = *scale_p;
    const int crow0 = brow + wm * 128 + ((lane >> 4) << 2);
    const int ccol0 = bcol + wn * 64 + (lane & 15);
    float bv[4];
#pragma unroll
    for (int nf = 0; nf < 4; ++nf) bv[nf] = bias[ccol0 + nf * 16];
#pragma unroll
    for (int mf = 0; mf < 8; ++mf) {
#pragma unroll
        for (int j = 0; j < 4; ++j) {
            const int r = crow0 + mf * 16 + j;
            const float s2 = scale * sx[r];
            float* orow = out + (size_t)r * N_DIM;
#pragma unroll
            for (int nf = 0; nf < 4; ++nf)
                orow[ccol0 + nf * 16] = (float)acc[mf][nf][j] * s2 + bv[nf];
        }
    }
}

// ---------------- fallback (ws too small): fused dequant 128^2 bf16 GEMM ------
__global__ __launch_bounds__(256)
void gemm_fb_kernel(const float* __restrict__ Xf, const int* __restrict__ Wq,
                    const float* __restrict__ bias,
                    const float* __restrict__ scale_p,
                    const int* __restrict__ zp_p,
                    float* __restrict__ out) {
    const int NB = N_DIM / 128;
    int nwg = gridDim.x;
    int cpx = nwg >> 3;
    int bid = blockIdx.x;
    int swz = (bid & 7) * cpx + (bid >> 3);
    int bx = swz % NB;
    int by = swz / NB;
    const int brow = by * 128;
    const int bcol = bx * 128;

    __shared__ __align__(16) ushort sA[128 * 32];
    __shared__ __align__(16) ushort sB[128 * 32];

    const int t = threadIdx.x;
    const int lane = t & 63;
    const int wid = t >> 6;
    const int wr = wid >> 1;
    const int wc = wid & 1;

    floatx4 acc[4][4] = {};

    const int xr = t >> 1;
    const int xc = (t & 1) << 4;
    const int zp = *zp_p;

    const int arow = wr * 64 + (lane & 15);
    const int acol = (lane >> 4) << 3;
    const int brow_f = wc * 64 + (lane & 15);

    for (int k0 = 0; k0 < K_DIM; k0 += 32) {
        __syncthreads();
        const float* gx = Xf + (size_t)(brow + xr) * K_DIM + k0 + xc;
        ushort* dA = &sA[xr * 32 + xc];
#pragma unroll
        for (int i = 0; i < 4; ++i) {
            float4 v = ((const float4*)gx)[i];
            ushort4 u;
            u.x = f2bf(v.x); u.y = f2bf(v.y); u.z = f2bf(v.z); u.w = f2bf(v.w);
            *(ushort4*)(dA + i * 4) = u;
        }
        const int* gw = Wq + (size_t)(bcol + xr) * K_DIM + k0 + xc;
        ushort* dB = &sB[xr * 32 + xc];
#pragma unroll
        for (int i = 0; i < 4; ++i) {
            int4 q = ((const int4*)gw)[i];
            ushort4 u;
            u.x = f2bf((float)(q.x - zp));
            u.y = f2bf((float)(q.y - zp));
            u.z = f2bf((float)(q.z - zp));
            u.w = f2bf((float)(q.w - zp));
            *(ushort4*)(dB + i * 4) = u;
        }
        __syncthreads();

        short8 af[4], bfr[4];
#pragma unroll
        for (int m = 0; m < 4; ++m)
            af[m] = *(const short8*)&sA[(arow + m * 16) * 32 + acol];
#pragma unroll
        for (int n = 0; n < 4; ++n)
            bfr[n] = *(const short8*)&sB[(brow_f + n * 16) * 32 + acol];

#pragma unroll
        for (int m = 0; m < 4; ++m)
#pragma unroll
            for (int n = 0; n < 4; ++n)
                acc[m][n] = __builtin_amdgcn_mfma_f32_16x16x32_bf16(
                    af[m], bfr[n], acc[m][n], 0, 0, 0);
    }

    const float scale = *scale_p;
    const int colbase = bcol + wc * 64 + (lane & 15);
    const int rowbase = brow + wr * 64 + ((lane >> 4) << 2);
    float bv[4];
#pragma unroll
    for (int n = 0; n < 4; ++n) bv[n] = bias[colbase + n * 16];
#pragma unroll
    for (int m = 0; m < 4; ++m) {
        const int r0 = rowbase + m * 16;
#pragma unroll
        for (int j = 0; j < 4; ++j) {
            float* orow = out + (size_t)(r0 + j) * N_DIM;
#pragma unroll
            for (int n = 0; n < 4; ++n)
                orow[colbase + n * 16] = acc[m][n][j] * scale + bv[n];
        }
    }
}

extern "C" void kernel_launch(void* const* d_in, const int* in_sizes, int n_in,
                              void* d_out, int out_size, void* d_ws, size_t ws_size,
                              hipStream_t stream) {
    const float* x = (const float*)d_in[0];
    const int* wq = (const int*)d_in[1];
    const float* bias = (const float*)d_in[2];
    const float* scale = (const float*)d_in[3];
    const int* zp = (const int*)d_in[4];
    float* out = (float*)d_out;

    const size_t xq_bytes = (size_t)M_DIM * K_DIM;       // 32 MiB
    const size_t wb_bytes = (size_t)N_DIM * K_DIM;       // 64 MiB
    const size_t sx_bytes = (size_t)M_DIM * 4;           // 32 KiB

    if (ws_size >= xq_bytes + wb_bytes + sx_bytes) {
        int8_t* xq = (int8_t*)d_ws;
        int8_t* wb = (int8_t*)d_ws + xq_bytes;
        float* sx = (float*)((char*)d_ws + xq_bytes + wb_bytes);
        quant_x_kernel<<<M_DIM, 256, 0, stream>>>((const float4*)x, (int*)xq, sx);
        cvt_w8_kernel<<<2048, 256, 0, stream>>>((const int4*)wq, (int4*)wb, zp,
                                                (N_DIM * K_DIM) / 16);
        const int nblocks = (M_DIM / 256) * (N_DIM / 256);  // 2048
        gemm8i_kernel<<<nblocks, 512, 0, stream>>>(xq, wb, bias, scale, sx, out);
    } else {
        const int nblocks = (M_DIM / 128) * (N_DIM / 128);
        gemm_fb_kernel<<<nblocks, 256, 0, stream>>>(x, wq, bias, scale, zp, out);
    }
}

// Round 9
// 692.611 us; speedup vs baseline: 2.0029x; 1.8105x over previous
//
#include <hip/hip_runtime.h>
#include <hip/hip_bf16.h>
#include <stdint.h>

#define M_DIM 8192
#define N_DIM 16384
#define K_DIM 4096

typedef short short8 __attribute__((ext_vector_type(8)));
typedef float floatx4 __attribute__((ext_vector_type(4)));
typedef int i32x4 __attribute__((ext_vector_type(4)));

__device__ __forceinline__ unsigned short f2bf(float f) {
    union { float f; unsigned u; } a;
    a.f = f;
    unsigned r = a.u + 0x7FFFu + ((a.u >> 16) & 1u);
    return (unsigned short)(r >> 16);
}

#define GLDS16(g, l)                                                     \
    __builtin_amdgcn_global_load_lds(                                    \
        (const __attribute__((address_space(1))) void*)(g),              \
        (__attribute__((address_space(3))) void*)(l), 16, 0, 0)

#define SBAR() asm volatile("s_barrier" ::: "memory")
#define WAIT_VM0() asm volatile("s_waitcnt vmcnt(0)" ::: "memory")
#define WAIT_VM8() asm volatile("s_waitcnt vmcnt(8)" ::: "memory")
#define SCHEDB() __builtin_amdgcn_sched_barrier(0)

// ---------------- x: per-row int8 quant (scale sx[row] = absmax/127) ----------
__global__ __launch_bounds__(256)
void quant_x_kernel(const float4* __restrict__ x, int* __restrict__ xq,
                    float* __restrict__ sx) {
    const int row = blockIdx.x;
    const int t = threadIdx.x;
    const float4* px = x + (size_t)row * (K_DIM / 4);
    float4 v[4];
    float am = 0.f;
#pragma unroll
    for (int j = 0; j < 4; ++j) {
        v[j] = px[t + j * 256];
        am = fmaxf(am, fmaxf(fmaxf(fabsf(v[j].x), fabsf(v[j].y)),
                             fmaxf(fabsf(v[j].z), fabsf(v[j].w))));
    }
#pragma unroll
    for (int m = 32; m; m >>= 1) am = fmaxf(am, __shfl_xor(am, m));
    __shared__ float red[4];
    if ((t & 63) == 0) red[t >> 6] = am;
    __syncthreads();
    am = fmaxf(fmaxf(red[0], red[1]), fmaxf(red[2], red[3]));
    const float inv = am > 0.f ? 127.f / am : 0.f;
    if (t == 0) sx[row] = am * (1.f / 127.f);
    int* xo = xq + (size_t)row * (K_DIM / 4);
#pragma unroll
    for (int j = 0; j < 4; ++j) {
        int q0 = (int)rintf(v[j].x * inv);
        int q1 = (int)rintf(v[j].y * inv);
        int q2 = (int)rintf(v[j].z * inv);
        int q3 = (int)rintf(v[j].w * inv);
        xo[t + j * 256] = (q0 & 255) | ((q1 & 255) << 8) |
                          ((q2 & 255) << 16) | ((q3 & 255) << 24);
    }
}

// ---------------- w: int32 -> int8 (q - zp), exact ----------------
__global__ void cvt_w8_kernel(const int4* __restrict__ w, int4* __restrict__ out,
                              const int* __restrict__ zp_p, int n16) {
    const int zp = *zp_p;
    int idx = blockIdx.x * blockDim.x + threadIdx.x;
    int stride = gridDim.x * blockDim.x;
    for (int i = idx; i < n16; i += stride) {
        int4 r;
        int* rp = (int*)&r;
#pragma unroll
        for (int j = 0; j < 4; ++j) {
            int4 q = w[i * 4 + j];
            rp[j] = ((q.x - zp) & 255) | (((q.y - zp) & 255) << 8) |
                    (((q.z - zp) & 255) << 16) | (((q.w - zp) & 255) << 24);
        }
        out[i] = r;
    }
}

// ====== 256x256 int8 GEMM: single-window body at R4 register footprint =======
// LDS layout / swizzle / staging addresses identical to R4 (verified, clean:
// WRITE_SIZE=524MB, VGPR=124). Body(kt), buf b=kt&1:
//   WAIT_VM8 (retire own body-(kt-2) staging -> tile kt resident) -> SBAR ->
//   ONE window, quadrant path Q00->Q01->Q11->Q10 with ONE shared A set:
//     load {aF<-A0, bF0, bF1}; Q00; Q01; [sched_barrier] reload aF<-A1 in the
//     SAME regs (WAR pins order; sched_barrier blocks a rename+hoist that
//     would recreate R8's 96-live-reg spill); Q11; Q10.
//   -> SBAR -> stage buf b for tile kt+2 (8 gloads, WAR-safe behind barrier).
// 2 barriers/K-tile; max-live fragments = 64 VGPR (A 32 + B0 16 + B1 16).
// Cross-wave slip inside the window overlaps LDS-port time with MFMA-pipe
// time (8 waves desynchronize between the two barriers) at ZERO register cost.

#define LOAD_AR(BUF, MH, AF)                                               \
    do {                                                                   \
        const char* p_ = smem + (BUF)*65536 + (MH)*16384 + wm*8192;        \
        _Pragma("unroll") for (int mf = 0; mf < 4; ++mf) {                 \
            AF[mf][0] = *(const i32x4*)(p_ + mf*2048 + laneK0);            \
            AF[mf][1] = *(const i32x4*)(p_ + mf*2048 + laneK1);            \
        }                                                                  \
    } while (0)

#define LOAD_BR(BUF, NH, BF)                                               \
    do {                                                                   \
        const char* p_ = smem + (BUF)*65536 + 32768 + (NH)*16384 + wn*4096;\
        _Pragma("unroll") for (int nf = 0; nf < 2; ++nf) {                 \
            BF[nf][0] = *(const i32x4*)(p_ + nf*2048 + laneK0);            \
            BF[nf][1] = *(const i32x4*)(p_ + nf*2048 + laneK1);            \
        }                                                                  \
    } while (0)

#define STAGE_A0(BUF)                                                      \
    do {                                                                   \
        GLDS16(pA00, smem + (BUF)*65536 + st16); pA00 += 128;              \
        GLDS16(pA01, smem + (BUF)*65536 + 8192 + st16); pA01 += 128;       \
    } while (0)
#define STAGE_A1(BUF)                                                      \
    do {                                                                   \
        GLDS16(pA10, smem + (BUF)*65536 + 16384 + st16); pA10 += 128;      \
        GLDS16(pA11, smem + (BUF)*65536 + 16384 + 8192 + st16); pA11 += 128;\
    } while (0)
#define STAGE_B0(BUF)                                                      \
    do {                                                                   \
        GLDS16(pB00, smem + (BUF)*65536 + 32768 + st16); pB00 += 128;      \
        GLDS16(pB01, smem + (BUF)*65536 + 32768 + 8192 + st16); pB01 += 128;\
    } while (0)
#define STAGE_B1(BUF)                                                      \
    do {                                                                   \
        GLDS16(pB10, smem + (BUF)*65536 + 49152 + st16); pB10 += 128;      \
        GLDS16(pB11, smem + (BUF)*65536 + 49152 + 8192 + st16); pB11 += 128;\
    } while (0)

#define MFMA_Q(AF, BF, MH, NH)                                             \
    do {                                                                   \
        __builtin_amdgcn_s_setprio(1);                                     \
        _Pragma("unroll") for (int kk = 0; kk < 2; ++kk)                   \
        _Pragma("unroll") for (int mf = 0; mf < 4; ++mf)                   \
        _Pragma("unroll") for (int nf = 0; nf < 2; ++nf)                   \
            acc[(MH)*4+mf][(NH)*2+nf] =                                    \
                __builtin_amdgcn_mfma_i32_16x16x64_i8(                     \
                    AF[mf][kk], BF[nf][kk], acc[(MH)*4+mf][(NH)*2+nf],     \
                    0, 0, 0);                                              \
        __builtin_amdgcn_s_setprio(0);                                     \
    } while (0)

// SMODE: 2 = steady (VM8 + stage kt+2); 1 = kt==NT-2 (VM8, no stage);
//        0 = kt==NT-1 (VM0, no stage).
#define BODY(B, SMODE)                                                     \
    do {                                                                   \
        if ((SMODE) == 0) { WAIT_VM0(); } else { WAIT_VM8(); }             \
        SBAR();                                                            \
        LOAD_AR(B, 0, aF);                                                 \
        LOAD_BR(B, 0, bF0);                                                \
        LOAD_BR(B, 1, bF1);                                                \
        MFMA_Q(aF, bF0, 0, 0);                                             \
        MFMA_Q(aF, bF1, 0, 1);                                             \
        SCHEDB();                                                          \
        LOAD_AR(B, 1, aF);                                                 \
        MFMA_Q(aF, bF1, 1, 1);                                             \
        MFMA_Q(aF, bF0, 1, 0);                                             \
        SBAR();                                                            \
        if ((SMODE) == 2) {                                                \
            STAGE_A0(B); STAGE_B0(B); STAGE_B1(B); STAGE_A1(B);            \
        }                                                                  \
    } while (0)

__global__ __launch_bounds__(512, 2)
void gemm8i_kernel(const int8_t* __restrict__ Aq, const int8_t* __restrict__ Bq,
                   const float* __restrict__ bias,
                   const float* __restrict__ scale_p,
                   const float* __restrict__ sx,
                   float* __restrict__ out) {
    __shared__ __align__(16) char smem[131072];

    const int t = threadIdx.x;
    const int lane = t & 63;
    const int wid = t >> 6;
    const int wm = wid >> 2;  // 0..1
    const int wn = wid & 3;   // 0..3

    // XCD-aware bijective swizzle (nwg=2048 divisible by 8)
    int bid = blockIdx.x;
    int sz = (bid & 7) * 256 + (bid >> 3);
    const int bx = sz & 63;
    const int by = sz >> 6;
    const int brow = by << 8;
    const int bcol = bx << 8;

    // swizzled ds_read lane offsets (128B rows, 16B slots)
    const int laneK0 = (lane & 15) * 128 + (((lane >> 4) * 16) ^ ((lane & 7) << 4));
    const int laneK1 = (lane & 15) * 128 + ((((lane >> 4) * 16) + 64) ^ ((lane & 7) << 4));

    // staging source offsets (inverse-swizzled); 1 byte per element
    size_t aoffs[2], boffs[2];
#pragma unroll
    for (int g = 0; g < 2; ++g) {
        unsigned u = g * 8192 + t * 16;
        unsigned up = u ^ (((u >> 7) & 7) << 4);
        aoffs[g] = (size_t)(brow + ((up >> 13) & 1) * 128 + ((up >> 7) & 63)) * K_DIM
                   + (up & 127);
        boffs[g] = (size_t)(bcol + ((up >> 12) & 3) * 64 + ((up >> 7) & 31)) * K_DIM
                   + (up & 127);
    }
    const int8_t* pA00 = Aq + aoffs[0];
    const int8_t* pA01 = Aq + aoffs[1];
    const int8_t* pA10 = Aq + aoffs[0] + 262144;   // +64 rows
    const int8_t* pA11 = Aq + aoffs[1] + 262144;
    const int8_t* pB00 = Bq + boffs[0];
    const int8_t* pB01 = Bq + boffs[1];
    const int8_t* pB10 = Bq + boffs[0] + 131072;   // +32 cols
    const int8_t* pB11 = Bq + boffs[1] + 131072;
    const int st16 = t * 16;

    i32x4 acc[8][4] = {};
    i32x4 aF[4][2], bF0[2][2], bF1[2][2];

    const int NT = K_DIM / 128;  // 32

    // ---- prologue: stage tile0 -> buf0, tile1 -> buf1 (16 loads, no wait)
    STAGE_A0(0); STAGE_B0(0); STAGE_B1(0); STAGE_A1(0);
    STAGE_A0(1); STAGE_B0(1); STAGE_B1(1); STAGE_A1(1);

    // ---- main loop: bodies 0..29 steady, branchless
    for (int it = 0; it < (NT - 2) / 2; ++it) {
        BODY(0, 2);
        BODY(1, 2);
    }
    // ---- tail: kt = NT-2 (buf0, no stage), kt = NT-1 (buf1, full drain)
    BODY(0, 1);
    BODY(1, 0);

    // ---- epilogue: out = acc * (scale*sx[row]) + bias[col]
    const float scale = *scale_p;
    const int crow0 = brow + wm * 128 + ((lane >> 4) << 2);
    const int ccol0 = bcol + wn * 64 + (lane & 15);
    float bv[4];
#pragma unroll
    for (int nf = 0; nf < 4; ++nf) bv[nf] = bias[ccol0 + nf * 16];
#pragma unroll
    for (int mf = 0; mf < 8; ++mf) {
#pragma unroll
        for (int j = 0; j < 4; ++j) {
            const int r = crow0 + mf * 16 + j;
            const float s2 = scale * sx[r];
            float* orow = out + (size_t)r * N_DIM;
#pragma unroll
            for (int nf = 0; nf < 4; ++nf)
                orow[ccol0 + nf * 16] = (float)acc[mf][nf][j] * s2 + bv[nf];
        }
    }
}

// ---------------- fallback (ws too small): fused dequant 128^2 bf16 GEMM ------
__global__ __launch_bounds__(256)
void gemm_fb_kernel(const float* __restrict__ Xf, const int* __restrict__ Wq,
                    const float* __restrict__ bias,
                    const float* __restrict__ scale_p,
                    const int* __restrict__ zp_p,
                    float* __restrict__ out) {
    const int NB = N_DIM / 128;
    int nwg = gridDim.x;
    int cpx = nwg >> 3;
    int bid = blockIdx.x;
    int swz = (bid & 7) * cpx + (bid >> 3);
    int bx = swz % NB;
    int by = swz / NB;
    const int brow = by * 128;
    const int bcol = bx * 128;

    __shared__ __align__(16) ushort sA[128 * 32];
    __shared__ __align__(16) ushort sB[128 * 32];

    const int t = threadIdx.x;
    const int lane = t & 63;
    const int wid = t >> 6;
    const int wr = wid >> 1;
    const int wc = wid & 1;

    floatx4 acc[4][4] = {};

    const int xr = t >> 1;
    const int xc = (t & 1) << 4;
    const int zp = *zp_p;

    const int arow = wr * 64 + (lane & 15);
    const int acol = (lane >> 4) << 3;
    const int brow_f = wc * 64 + (lane & 15);

    for (int k0 = 0; k0 < K_DIM; k0 += 32) {
        __syncthreads();
        const float* gx = Xf + (size_t)(brow + xr) * K_DIM + k0 + xc;
        ushort* dA = &sA[xr * 32 + xc];
#pragma unroll
        for (int i = 0; i < 4; ++i) {
            float4 v = ((const float4*)gx)[i];
            ushort4 u;
            u.x = f2bf(v.x); u.y = f2bf(v.y); u.z = f2bf(v.z); u.w = f2bf(v.w);
            *(ushort4*)(dA + i * 4) = u;
        }
        const int* gw = Wq + (size_t)(bcol + xr) * K_DIM + k0 + xc;
        ushort* dB = &sB[xr * 32 + xc];
#pragma unroll
        for (int i = 0; i < 4; ++i) {
            int4 q = ((const int4*)gw)[i];
            ushort4 u;
            u.x = f2bf((float)(q.x - zp));
            u.y = f2bf((float)(q.y - zp));
            u.z = f2bf((float)(q.z - zp));
            u.w = f2bf((float)(q.w - zp));
            *(ushort4*)(dB + i * 4) = u;
        }
        __syncthreads();

        short8 af[4], bfr[4];
#pragma unroll
        for (int m = 0; m < 4; ++m)
            af[m] = *(const short8*)&sA[(arow + m * 16) * 32 + acol];
#pragma unroll
        for (int n = 0; n < 4; ++n)
            bfr[n] = *(const short8*)&sB[(brow_f + n * 16) * 32 + acol];

#pragma unroll
        for (int m = 0; m < 4; ++m)
#pragma unroll
            for (int n = 0; n < 4; ++n)
                acc[m][n] = __builtin_amdgcn_mfma_f32_16x16x32_bf16(
                    af[m], bfr[n], acc[m][n], 0, 0, 0);
    }

    const float scale = *scale_p;
    const int colbase = bcol + wc * 64 + (lane & 15);
    const int rowbase = brow + wr * 64 + ((lane >> 4) << 2);
    float bv[4];
#pragma unroll
    for (int n = 0; n < 4; ++n) bv[n] = bias[colbase + n * 16];
#pragma unroll
    for (int m = 0; m < 4; ++m) {
        const int r0 = rowbase + m * 16;
#pragma unroll
        for (int j = 0; j < 4; ++j) {
            float* orow = out + (size_t)(r0 + j) * N_DIM;
#pragma unroll
            for (int n = 0; n < 4; ++n)
                orow[colbase + n * 16] = acc[m][n][j] * scale + bv[n];
        }
    }
}

extern "C" void kernel_launch(void* const* d_in, const int* in_sizes, int n_in,
                              void* d_out, int out_size, void* d_ws, size_t ws_size,
                              hipStream_t stream) {
    const float* x = (const float*)d_in[0];
    const int* wq = (const int*)d_in[1];
    const float* bias = (const float*)d_in[2];
    const float* scale = (const float*)d_in[3];
    const int* zp = (const int*)d_in[4];
    float* out = (float*)d_out;

    const size_t xq_bytes = (size_t)M_DIM * K_DIM;       // 32 MiB
    const size_t wb_bytes = (size_t)N_DIM * K_DIM;       // 64 MiB
    const size_t sx_bytes = (size_t)M_DIM * 4;           // 32 KiB

    if (ws_size >= xq_bytes + wb_bytes + sx_bytes) {
        int8_t* xq = (int8_t*)d_ws;
        int8_t* wb = (int8_t*)d_ws + xq_bytes;
        float* sx = (float*)((char*)d_ws + xq_bytes + wb_bytes);
        quant_x_kernel<<<M_DIM, 256, 0, stream>>>((const float4*)x, (int*)xq, sx);
        cvt_w8_kernel<<<2048, 256, 0, stream>>>((const int4*)wq, (int4*)wb, zp,
                                                (N_DIM * K_DIM) / 16);
        const int nblocks = (M_DIM / 256) * (N_DIM / 256);  // 2048
        gemm8i_kernel<<<nblocks, 512, 0, stream>>>(xq, wb, bias, scale, sx, out);
    } else {
        const int nblocks = (M_DIM / 128) * (N_DIM / 128);
        gemm_fb_kernel<<<nblocks, 256, 0, stream>>>(x, wq, bias, scale, zp, out);
    }
}